// Round 7
// baseline (1453.939 us; speedup 1.0000x reference)
//
#include <hip/hip_runtime.h>
#include <hip/hip_bf16.h>
#include <math.h>

// ---------- types ----------
typedef __bf16 bf16x8 __attribute__((ext_vector_type(8)));
typedef _Float16 f16x8 __attribute__((ext_vector_type(8)));
typedef float  f32x4  __attribute__((ext_vector_type(4)));

#define GLB_AS(p) ((const __attribute__((address_space(1))) void*)(p))
#define LDS_AS(p) ((__attribute__((address_space(3))) void*)(p))

__device__ __forceinline__ double shfl_xor_dbl(double v, int m) {
    union { double d; int i[2]; } u;
    u.d = v;
    u.i[0] = __shfl_xor(u.i[0], m);
    u.i[1] = __shfl_xor(u.i[1], m);
    return u.d;
}

// ---------- f32 -> bf16 convert (plain weights) ----------
__global__ __launch_bounds__(256) void cvt_kernel(const float* __restrict__ in,
                                                  __hip_bfloat16* __restrict__ o) {
    const int i = blockIdx.x * 256 + threadIdx.x;
    const float4 v = ((const float4*)in)[i];
    __hip_bfloat16* p = o + (size_t)i * 4;
    p[0] = __float2bfloat16(v.x);
    p[1] = __float2bfloat16(v.y);
    p[2] = __float2bfloat16(v.z);
    p[3] = __float2bfloat16(v.w);
}

// ---------- qkv weight gather + fp16 hi/lo split (lo pre-scaled x1024) ----------
template <int OFS, bool HAS_LO>
__global__ __launch_bounds__(256) void cvt_split_kernel(const float* __restrict__ w,
                                                        _Float16* __restrict__ hi,
                                                        _Float16* __restrict__ lo) {
    const int j = blockIdx.x;
    const int src = (j >> 6) * 192 + OFS + (j & 63);
    const float4 v = ((const float4*)(w + (size_t)src * 1024))[threadIdx.x];
    _Float16 h0 = (_Float16)v.x, h1 = (_Float16)v.y, h2 = (_Float16)v.z, h3 = (_Float16)v.w;
    _Float16* hp = hi + (size_t)j * 1024 + threadIdx.x * 4;
    hp[0] = h0; hp[1] = h1; hp[2] = h2; hp[3] = h3;
    if (HAS_LO) {
        _Float16* lp = lo + (size_t)j * 1024 + threadIdx.x * 4;
        lp[0] = (_Float16)((v.x - (float)h0) * 1024.f);
        lp[1] = (_Float16)((v.y - (float)h1) * 1024.f);
        lp[2] = (_Float16)((v.z - (float)h2) * 1024.f);
        lp[3] = (_Float16)((v.w - (float)h3) * 1024.f);
    }
}

// ---------- LayerNorm f32 -> fp16 hi/lo (lo x1024), C=1024 ----------
__global__ __launch_bounds__(256) void ln_split_kernel(const float* __restrict__ x,
                                                       const float* __restrict__ w,
                                                       const float* __restrict__ b,
                                                       _Float16* __restrict__ yh,
                                                       _Float16* __restrict__ yl) {
    const int row = blockIdx.x;
    const int t = threadIdx.x;
    const float4 v = ((const float4*)(x + (size_t)row * 1024))[t];
    float s1 = v.x + v.y + v.z + v.w;
    float s2 = v.x * v.x + v.y * v.y + v.z * v.z + v.w * v.w;
#pragma unroll
    for (int off = 32; off; off >>= 1) {
        s1 += __shfl_xor(s1, off);
        s2 += __shfl_xor(s2, off);
    }
    __shared__ float red[8];
    const int wid = t >> 6, lane = t & 63;
    if (lane == 0) { red[wid] = s1; red[4 + wid] = s2; }
    __syncthreads();
    s1 = red[0] + red[1] + red[2] + red[3];
    s2 = red[4] + red[5] + red[6] + red[7];
    const float mu = s1 * (1.f / 1024.f);
    const float var = s2 * (1.f / 1024.f) - mu * mu;
    const float rs = rsqrtf(var + 1e-5f);
    const float4 wv = ((const float4*)w)[t];
    const float4 bv = ((const float4*)b)[t];
    float y[4] = {(v.x - mu) * rs * wv.x + bv.x, (v.y - mu) * rs * wv.y + bv.y,
                  (v.z - mu) * rs * wv.z + bv.z, (v.w - mu) * rs * wv.w + bv.w};
    _Float16* hp = yh + (size_t)row * 1024 + t * 4;
    _Float16* lp = yl + (size_t)row * 1024 + t * 4;
#pragma unroll
    for (int j = 0; j < 4; ++j) {
        _Float16 h = (_Float16)y[j];
        hp[j] = h;
        lp[j] = (_Float16)((y[j] - (float)h) * 1024.f);
    }
}

// ---------- LayerNorm f32 -> bf16 (LN2) ----------
__global__ __launch_bounds__(256) void ln_kernel(const float* __restrict__ x,
                                                 const float* __restrict__ w,
                                                 const float* __restrict__ b,
                                                 __hip_bfloat16* __restrict__ y) {
    const int row = blockIdx.x;
    const int t = threadIdx.x;
    const float4 v = ((const float4*)(x + (size_t)row * 1024))[t];
    float s1 = v.x + v.y + v.z + v.w;
    float s2 = v.x * v.x + v.y * v.y + v.z * v.z + v.w * v.w;
#pragma unroll
    for (int off = 32; off; off >>= 1) {
        s1 += __shfl_xor(s1, off);
        s2 += __shfl_xor(s2, off);
    }
    __shared__ float red[8];
    const int wid = t >> 6, lane = t & 63;
    if (lane == 0) { red[wid] = s1; red[4 + wid] = s2; }
    __syncthreads();
    s1 = red[0] + red[1] + red[2] + red[3];
    s2 = red[4] + red[5] + red[6] + red[7];
    const float mu = s1 * (1.f / 1024.f);
    const float var = s2 * (1.f / 1024.f) - mu * mu;
    const float rs = rsqrtf(var + 1e-5f);
    const float4 wv = ((const float4*)w)[t];
    const float4 bv = ((const float4*)b)[t];
    __hip_bfloat16* yp = y + (size_t)row * 1024 + t * 4;
    yp[0] = __float2bfloat16((v.x - mu) * rs * wv.x + bv.x);
    yp[1] = __float2bfloat16((v.y - mu) * rs * wv.y + bv.y);
    yp[2] = __float2bfloat16((v.z - mu) * rs * wv.z + bv.z);
    yp[3] = __float2bfloat16((v.w - mu) * rs * wv.w + bv.w);
}

// ---------- fp16x2 split GEMM (q/k) and fp16 GEMM (v). M=16384, N=1024, K=1024 ----------
// raw = [acc0a + acc0b](f64 combine) + (Ah*Bl + Al*Bh)/1024 + bias
// EPI 0: q: K-split acc (512+512); silu f64; den[row][h] = sum_d silu(q)*ksum_d (f64)
// EPI 1: k: silu f64 for kcol; f16 out; per-block col partials -> kpart
// EPI 2: v: f16 out (hi product only)
template <int EPI>
__global__ __launch_bounds__(256) void gemm_f16(const _Float16* __restrict__ Ah,
                                                const _Float16* __restrict__ Al,
                                                const _Float16* __restrict__ Bh,
                                                const _Float16* __restrict__ Bl,
                                                const float* __restrict__ qkvb,
                                                _Float16* __restrict__ outp,
                                                const double* __restrict__ ksum_in,
                                                float* __restrict__ kpart,
                                                double* __restrict__ den_out) {
    const int K = 1024;
    constexpr int KSPLIT = (EPI == 0) ? 512 : 1024;
    __shared__ __align__(16) _Float16 AsH[128 * 32];
    __shared__ __align__(16) _Float16 BsH[128 * 32];
    __shared__ __align__(16) _Float16 AsL[128 * 32];
    __shared__ __align__(16) _Float16 BsL[128 * 32];
    __shared__ float kl[8][128];
    const int tid = threadIdx.x;
    const int wid = tid >> 6;
    const int lane = tid & 63;
    const int bm = blockIdx.x, bn = blockIdx.y;
    const int wr = (wid >> 1) * 64;
    const int wc = (wid & 1) * 64;
    const int l15 = lane & 15;
    const int lhi = lane >> 4;

    f32x4 acc0a[4][4] = {};
    f32x4 acc0b[4][4] = {};
    f32x4 acc1[4][4] = {};

    const int row0 = tid >> 2, colb0 = (tid & 3) * 16;
    const size_t rowstride = (size_t)K * 2;
    const char* AhB = (const char*)(Ah + (size_t)(bm * 128) * K);
    const char* BhB = (const char*)(Bh + (size_t)(bn * 128) * K);
    const char* AlB = (const char*)(Al + (size_t)(bm * 128) * K);
    const char* BlB = (const char*)(Bl + (size_t)(bn * 128) * K);

    auto kstep = [&](int k0, f32x4 (&accH)[4][4]) {
        const size_t koff = (size_t)k0 * 2;
        const size_t o0 = (size_t)row0 * rowstride + koff + colb0;
        const size_t o1 = o0 + 64 * rowstride;
        __builtin_amdgcn_global_load_lds(GLB_AS(AhB + o0), LDS_AS((char*)AsH + wid * 1024), 16, 0, 0);
        __builtin_amdgcn_global_load_lds(GLB_AS(AhB + o1), LDS_AS((char*)AsH + 4096 + wid * 1024), 16, 0, 0);
        __builtin_amdgcn_global_load_lds(GLB_AS(BhB + o0), LDS_AS((char*)BsH + wid * 1024), 16, 0, 0);
        __builtin_amdgcn_global_load_lds(GLB_AS(BhB + o1), LDS_AS((char*)BsH + 4096 + wid * 1024), 16, 0, 0);
        if (EPI < 2) {
            __builtin_amdgcn_global_load_lds(GLB_AS(AlB + o0), LDS_AS((char*)AsL + wid * 1024), 16, 0, 0);
            __builtin_amdgcn_global_load_lds(GLB_AS(AlB + o1), LDS_AS((char*)AsL + 4096 + wid * 1024), 16, 0, 0);
            __builtin_amdgcn_global_load_lds(GLB_AS(BlB + o0), LDS_AS((char*)BsL + wid * 1024), 16, 0, 0);
            __builtin_amdgcn_global_load_lds(GLB_AS(BlB + o1), LDS_AS((char*)BsL + 4096 + wid * 1024), 16, 0, 0);
        }
        __syncthreads();

        f16x8 ah[4], bh[4], al[4], bl[4];
#pragma unroll
        for (int m = 0; m < 4; ++m) {
            ah[m] = *(const f16x8*)(AsH + (wr + m * 16 + l15) * 32 + lhi * 8);
            if (EPI < 2) al[m] = *(const f16x8*)(AsL + (wr + m * 16 + l15) * 32 + lhi * 8);
        }
#pragma unroll
        for (int n = 0; n < 4; ++n) {
            bh[n] = *(const f16x8*)(BsH + (wc + n * 16 + l15) * 32 + lhi * 8);
            if (EPI < 2) bl[n] = *(const f16x8*)(BsL + (wc + n * 16 + l15) * 32 + lhi * 8);
        }
#pragma unroll
        for (int m = 0; m < 4; ++m)
#pragma unroll
            for (int n = 0; n < 4; ++n) {
                accH[m][n] = __builtin_amdgcn_mfma_f32_16x16x32_f16(ah[m], bh[n], accH[m][n], 0, 0, 0);
                if (EPI < 2) {
                    acc1[m][n] = __builtin_amdgcn_mfma_f32_16x16x32_f16(ah[m], bl[n], acc1[m][n], 0, 0, 0);
                    acc1[m][n] = __builtin_amdgcn_mfma_f32_16x16x32_f16(al[m], bh[n], acc1[m][n], 0, 0, 0);
                }
            }
        __syncthreads();
    };

    for (int k0 = 0; k0 < KSPLIT; k0 += 32) kstep(k0, acc0a);
    for (int k0 = KSPLIT; k0 < K; k0 += 32) kstep(k0, acc0b);

    // epilogue. C/D: col = lane&15, row = (lane>>4)*4 + i
    const int rbase = bm * 128 + wr + lhi * 4;
    const int j0 = bn * 128 + wc + l15;          // output col (+ n*16)
    const int hh = (bn * 128 + wc) >> 6;         // head 0..15 (uniform per wave)
    const int bofs = (EPI == 0) ? 0 : (EPI == 1) ? 64 : 128;
    const int bb = (bm * 128) >> 12;             // batch index (uniform)
    const int kbase = bb * 1024 + hh * 64;

    double ks[4];
    if (EPI == 0) {
#pragma unroll
        for (int n = 0; n < 4; ++n) ks[n] = ksum_in[kbase + n * 16 + l15];
    }
    double kcol[4] = {};

#pragma unroll
    for (int m = 0; m < 4; ++m) {
#pragma unroll
        for (int i = 0; i < 4; ++i) {
            const int gr = rbase + m * 16 + i;
            double denv = 0.0;
#pragma unroll
            for (int n = 0; n < 4; ++n) {
                double qd = (double)acc0a[m][n][i] + (double)acc0b[m][n][i];
                if (EPI < 2) qd += (double)acc1[m][n][i] * (1.0 / 1024.0);
                qd += (double)qkvb[hh * 192 + bofs + n * 16 + l15];
                if (EPI < 2) {
                    const double sd = qd / (1.0 + exp(-qd));
                    outp[(size_t)gr * 1024 + j0 + n * 16] = (_Float16)(float)sd;
                    if (EPI == 0) denv += sd * ks[n];
                    if (EPI == 1) kcol[n] += sd;
                } else {
                    outp[(size_t)gr * 1024 + j0 + n * 16] = (_Float16)(float)qd;
                }
            }
            if (EPI == 0) {
                denv += shfl_xor_dbl(denv, 1);
                denv += shfl_xor_dbl(denv, 2);
                denv += shfl_xor_dbl(denv, 4);
                denv += shfl_xor_dbl(denv, 8);
                if (l15 == 0) den_out[(size_t)gr * 16 + hh] = denv;
            }
        }
    }
    if (EPI == 1) {
        const int part = (wr >> 6) * 4 + lhi;    // 0..7
#pragma unroll
        for (int n = 0; n < 4; ++n) kl[part][wc + n * 16 + l15] = (float)kcol[n];
        __syncthreads();
        if (tid < 128) {
            double s = 0.0;
#pragma unroll
            for (int p = 0; p < 8; ++p) s += (double)kl[p][tid];
            kpart[(size_t)bm * 1024 + bn * 128 + tid] = (float)s;
        }
    }
}

// ---------- ksum reduce: KSUM[b][col] = sum_{j<32} KPART[b*32+j][col], f64 ----------
__global__ __launch_bounds__(256) void ksum_reduce_kernel(const float* __restrict__ kpart,
                                                          double* __restrict__ ksum) {
    const int idx = blockIdx.x * 256 + threadIdx.x;   // [0,4096)
    const int b = idx >> 10, col = idx & 1023;
    double acc = 0.0;
    for (int j = 0; j < 32; ++j) acc += (double)kpart[(size_t)(b * 32 + j) * 1024 + col];
    ksum[idx] = acc;
}

// ---------- bf16 GEMM: C[m,n] = epi( sum_k A[m,k]*Bt[n,k] + bias[n] ) ----------
// EPI 1: +resid (f32), f32 out ; EPI 2: gelu exact, bf16 out
template <int EPI>
__global__ __launch_bounds__(256) void gemm_bt(const __hip_bfloat16* __restrict__ A,
                                               const __hip_bfloat16* __restrict__ Bt,
                                               const float* __restrict__ bias,
                                               const float* __restrict__ resid,
                                               void* __restrict__ outp,
                                               int M, int N, int K) {
    __shared__ __align__(16) __hip_bfloat16 As[128 * 32];
    __shared__ __align__(16) __hip_bfloat16 Bs[128 * 32];
    const int tid = threadIdx.x;
    const int wid = tid >> 6;
    const int lane = tid & 63;
    const int bm = blockIdx.x, bn = blockIdx.y;
    const int wr = (wid >> 1) * 64;
    const int wc = (wid & 1) * 64;
    const int l15 = lane & 15;
    const int lhi = lane >> 4;

    f32x4 acc[4][4] = {};

    const int row0 = tid >> 2, colb0 = (tid & 3) * 16;
    const char* Abase = (const char*)(A + (size_t)(bm * 128) * K);
    const char* Bbase = (const char*)(Bt + (size_t)(bn * 128) * K);
    const size_t rowstride = (size_t)K * 2;

    for (int k0 = 0; k0 < K; k0 += 32) {
        const size_t koff = (size_t)k0 * 2;
        const size_t o0 = (size_t)row0 * rowstride + koff + colb0;
        const size_t o1 = o0 + 64 * rowstride;
        __builtin_amdgcn_global_load_lds(GLB_AS(Abase + o0), LDS_AS((char*)As + wid * 1024), 16, 0, 0);
        __builtin_amdgcn_global_load_lds(GLB_AS(Abase + o1), LDS_AS((char*)As + 4096 + wid * 1024), 16, 0, 0);
        __builtin_amdgcn_global_load_lds(GLB_AS(Bbase + o0), LDS_AS((char*)Bs + wid * 1024), 16, 0, 0);
        __builtin_amdgcn_global_load_lds(GLB_AS(Bbase + o1), LDS_AS((char*)Bs + 4096 + wid * 1024), 16, 0, 0);
        __syncthreads();

        bf16x8 af[4], bf[4];
#pragma unroll
        for (int m = 0; m < 4; ++m)
            af[m] = *(const bf16x8*)(As + (wr + m * 16 + l15) * 32 + lhi * 8);
#pragma unroll
        for (int n = 0; n < 4; ++n)
            bf[n] = *(const bf16x8*)(Bs + (wc + n * 16 + l15) * 32 + lhi * 8);
#pragma unroll
        for (int m = 0; m < 4; ++m)
#pragma unroll
            for (int n = 0; n < 4; ++n)
                acc[m][n] = __builtin_amdgcn_mfma_f32_16x16x32_bf16(af[m], bf[n], acc[m][n], 0, 0, 0);
        __syncthreads();
    }

    const int rbase = bm * 128 + wr + lhi * 4;
    const int cbase = bn * 128 + wc + l15;
#pragma unroll
    for (int n = 0; n < 4; ++n) {
        const int gc = cbase + n * 16;
        const float bv = bias[gc];
#pragma unroll
        for (int m = 0; m < 4; ++m) {
#pragma unroll
            for (int i = 0; i < 4; ++i) {
                const int gr = rbase + m * 16 + i;
                const size_t o = (size_t)gr * N + gc;
                float v = acc[m][n][i] + bv;
                if (EPI == 1) {
                    ((float*)outp)[o] = v + resid[o];
                } else {
                    v = 0.5f * v * (1.f + erff(v * 0.70710678118f));
                    ((__hip_bfloat16*)outp)[o] = __float2bfloat16(v);
                }
            }
        }
    }
}

// ---------- attention state partials: s8[split][bh][d][e] = sum_n k*v over split ----------
// grid (64 bh, 8 splits), 256 thr. Kf/Vf: [16384][1024] f16, col = h*64+d
__global__ __launch_bounds__(256) void attn_state_kernel(const _Float16* __restrict__ Kf,
                                                         const _Float16* __restrict__ Vf,
                                                         float* __restrict__ s8) {
    const int bh = blockIdx.x;
    const int b = bh >> 4, h = bh & 15;
    const int n0 = blockIdx.y * 512;
    __shared__ float klds[64][64];
    __shared__ float vlds[64][64];
    const int t = threadIdx.x;
    const int r = t >> 2, cc = (t & 3) * 16;
    const int d = t >> 2, e0 = (t & 3) * 16;
    float s[16] = {};

    for (int c = 0; c < 512; c += 64) {
        const size_t m = (size_t)b * 4096 + n0 + c + r;
        const _Float16* kb = Kf + m * 1024 + h * 64;
        const _Float16* vb = Vf + m * 1024 + h * 64;
        const f16x8 k0 = *(const f16x8*)(kb + cc);
        const f16x8 k1 = *(const f16x8*)(kb + cc + 8);
        const f16x8 v0 = *(const f16x8*)(vb + cc);
        const f16x8 v1 = *(const f16x8*)(vb + cc + 8);
        __syncthreads();
#pragma unroll
        for (int j = 0; j < 8; ++j) {
            klds[r][cc + j]     = (float)k0[j];
            klds[r][cc + 8 + j] = (float)k1[j];
            vlds[r][cc + j]     = (float)v0[j];
            vlds[r][cc + 8 + j] = (float)v1[j];
        }
        __syncthreads();
#pragma unroll 8
        for (int n = 0; n < 64; ++n) {
            const float kk = klds[n][d];
            const float4* vp = (const float4*)&vlds[n][e0];
            const float4 a0 = vp[0], a1 = vp[1], a2 = vp[2], a3 = vp[3];
            s[0]  += kk * a0.x; s[1]  += kk * a0.y; s[2]  += kk * a0.z; s[3]  += kk * a0.w;
            s[4]  += kk * a1.x; s[5]  += kk * a1.y; s[6]  += kk * a1.z; s[7]  += kk * a1.w;
            s[8]  += kk * a2.x; s[9]  += kk * a2.y; s[10] += kk * a2.z; s[11] += kk * a2.w;
            s[12] += kk * a3.x; s[13] += kk * a3.y; s[14] += kk * a3.z; s[15] += kk * a3.w;
        }
    }
    float* sp = s8 + (((size_t)blockIdx.y * 64 + bh) * 64 + d) * 64 + e0;
#pragma unroll
    for (int j = 0; j < 16; ++j) sp[j] = s[j];
}

// ---------- state reduce: STATE[i] = sum_{j<8} S8[j][i] ----------
__global__ __launch_bounds__(256) void state_reduce_kernel(const float* __restrict__ s8,
                                                           float* __restrict__ state) {
    const int idx = blockIdx.x * 256 + threadIdx.x;  // [0, 262144)
    float a = 0.f;
#pragma unroll
    for (int j = 0; j < 8; ++j) a += s8[(size_t)j * 262144 + idx];
    state[idx] = a;
}

// ---------- attention out: out[n][e] = (sum_d q[n][d]*state[d][e]) / (den[n][h]+eps) ----------
__global__ __launch_bounds__(256) void attn_out_kernel(const _Float16* __restrict__ Qf,
                                                       const float* __restrict__ state,
                                                       const double* __restrict__ den,
                                                       __hip_bfloat16* __restrict__ aout) {
    const int bh = blockIdx.x;
    const int b = bh >> 4, h = bh & 15;
    const int n0 = blockIdx.y * 64;
    __shared__ float slds[64][64];
    __shared__ float qlds[64][65];
    const int t = threadIdx.x;
    {
        const float4* sp = (const float4*)(state + (size_t)bh * 4096);
        float4* dp = (float4*)&slds[0][0];
#pragma unroll
        for (int i = 0; i < 4; ++i) dp[i * 256 + t] = sp[i * 256 + t];
    }
    {
        const int r = t >> 2, cc = (t & 3) * 16;
        const size_t m = (size_t)b * 4096 + n0 + r;
        const _Float16* qb = Qf + m * 1024 + h * 64;
        const f16x8 q0 = *(const f16x8*)(qb + cc);
        const f16x8 q1 = *(const f16x8*)(qb + cc + 8);
#pragma unroll
        for (int j = 0; j < 8; ++j) {
            qlds[r][cc + j]     = (float)q0[j];
            qlds[r][cc + 8 + j] = (float)q1[j];
        }
    }
    __syncthreads();
    const int r = t >> 2, e0 = (t & 3) * 16;
    const size_t mrow = (size_t)b * 4096 + n0 + r;
    float o[16] = {};
#pragma unroll 8
    for (int dd = 0; dd < 64; ++dd) {
        const float qv = qlds[r][dd];
        const float4* sp4 = (const float4*)&slds[dd][e0];
        const float4 a0 = sp4[0], a1 = sp4[1], a2 = sp4[2], a3 = sp4[3];
        o[0]  += qv * a0.x; o[1]  += qv * a0.y; o[2]  += qv * a0.z; o[3]  += qv * a0.w;
        o[4]  += qv * a1.x; o[5]  += qv * a1.y; o[6]  += qv * a1.z; o[7]  += qv * a1.w;
        o[8]  += qv * a2.x; o[9]  += qv * a2.y; o[10] += qv * a2.z; o[11] += qv * a2.w;
        o[12] += qv * a3.x; o[13] += qv * a3.y; o[14] += qv * a3.z; o[15] += qv * a3.w;
    }
    const float inv = (float)(1.0 / (den[mrow * 16 + h] + 1e-6));
    __hip_bfloat16* op = aout + mrow * 1024 + h * 64 + e0;
#pragma unroll
    for (int j = 0; j < 16; ++j) op[j] = __float2bfloat16(o[j] * inv);
}

// ---------- launch ----------
extern "C" void kernel_launch(void* const* d_in, const int* in_sizes, int n_in,
                              void* d_out, int out_size, void* d_ws, size_t ws_size,
                              hipStream_t stream) {
    const float* x     = (const float*)d_in[0];
    const float* ln1_w = (const float*)d_in[1];
    const float* ln1_b = (const float*)d_in[2];
    const float* ln2_w = (const float*)d_in[3];
    const float* ln2_b = (const float*)d_in[4];
    const float* qkv_w = (const float*)d_in[5];
    const float* qkv_b = (const float*)d_in[6];
    const float* out_w = (const float*)d_in[7];
    const float* out_b = (const float*)d_in[8];
    const float* fc1_w = (const float*)d_in[9];
    const float* fc1_b = (const float*)d_in[10];
    const float* fc2_w = (const float*)d_in[11];
    const float* fc2_b = (const float*)d_in[12];
    float* out = (float*)d_out;

    char* ws = (char*)d_ws;
    _Float16* Wqh = (_Float16*)(ws + 0);
    _Float16* Wql = (_Float16*)(ws + 2097152);
    _Float16* Wkh = (_Float16*)(ws + 4194304);
    _Float16* Wkl = (_Float16*)(ws + 6291456);
    _Float16* Wvh = (_Float16*)(ws + 8388608);
    __hip_bfloat16* Wo = (__hip_bfloat16*)(ws + 10485760);
    __hip_bfloat16* W1 = (__hip_bfloat16*)(ws + 12582912);
    __hip_bfloat16* W2 = (__hip_bfloat16*)(ws + 20971520);
    _Float16* XH = (_Float16*)(ws + 29360128);          // ln1 hi; later: STATE8 overlay; later: ln2 out
    _Float16* XL = (_Float16*)(ws + 62914560);          // ln1 lo; later: AO bf16 / h
    _Float16* QF = (_Float16*)(ws + 96468992);
    _Float16* KF = (_Float16*)(ws + 130023424);
    _Float16* VF = (_Float16*)(ws + 163577856);
    double* DEN  = (double*)(ws + 197132288);           // [16384][16] f64, 2 MB
    float* KPART = (float*)(ws + 199229440);            // [128][1024] f32, 512 KB
    double* KSUM = (double*)(ws + 199753728);           // [4][1024] f64, 32 KB
    float* STATE = (float*)(ws + 199786496);            // [64][64][64] f32, 1 MB
    float* STATE8 = (float*)XH;                          // [8][64][64][64] f32, 8 MB (XH dead)
    __hip_bfloat16* AO   = (__hip_bfloat16*)XL;
    __hip_bfloat16* Hbuf = (__hip_bfloat16*)XL;
    __hip_bfloat16* XN2  = (__hip_bfloat16*)XH;

    cvt_split_kernel<0, true><<<1024, 256, 0, stream>>>(qkv_w, Wqh, Wql);
    cvt_split_kernel<64, true><<<1024, 256, 0, stream>>>(qkv_w, Wkh, Wkl);
    cvt_split_kernel<128, false><<<1024, 256, 0, stream>>>(qkv_w, Wvh, nullptr);
    cvt_kernel<<<1024, 256, 0, stream>>>(out_w, Wo);
    cvt_kernel<<<4096, 256, 0, stream>>>(fc1_w, W1);
    cvt_kernel<<<4096, 256, 0, stream>>>(fc2_w, W2);

    ln_split_kernel<<<16384, 256, 0, stream>>>(x, ln1_w, ln1_b, XH, XL);

    // k (kpart) -> ksum f64 -> q (den) ; v independent
    gemm_f16<1><<<dim3(128, 8), 256, 0, stream>>>(XH, XL, Wkh, Wkl, qkv_b, KF, nullptr, KPART, nullptr);
    ksum_reduce_kernel<<<16, 256, 0, stream>>>(KPART, KSUM);
    gemm_f16<0><<<dim3(128, 8), 256, 0, stream>>>(XH, XL, Wqh, Wql, qkv_b, QF, KSUM, nullptr, DEN);
    gemm_f16<2><<<dim3(128, 8), 256, 0, stream>>>(XH, nullptr, Wvh, nullptr, qkv_b, VF, nullptr, nullptr, nullptr);

    attn_state_kernel<<<dim3(64, 8), 256, 0, stream>>>(KF, VF, STATE8);
    state_reduce_kernel<<<1024, 256, 0, stream>>>(STATE8, STATE);
    attn_out_kernel<<<dim3(64, 64), 256, 0, stream>>>(QF, STATE, DEN, AO);

    // out proj + residual -> x2 (f32, in d_out)
    gemm_bt<1><<<dim3(128, 8), 256, 0, stream>>>(AO, Wo, out_b, x, out, 16384, 1024, 1024);
    // LN2
    ln_kernel<<<16384, 256, 0, stream>>>(out, ln2_w, ln2_b, XN2);
    // fc1 + gelu
    gemm_bt<2><<<dim3(128, 32), 256, 0, stream>>>(XN2, W1, fc1_b, nullptr, Hbuf, 16384, 4096, 1024);
    // fc2 + bias + residual -> final out
    gemm_bt<1><<<dim3(128, 8), 256, 0, stream>>>(Hbuf, W2, fc2_b, out, out, 16384, 1024, 4096);
}

// Round 9
// 1276.682 us; speedup vs baseline: 1.1388x; 1.1388x over previous
//
#include <hip/hip_runtime.h>
#include <hip/hip_bf16.h>
#include <math.h>

// ---------- types ----------
typedef __bf16 bf16x8 __attribute__((ext_vector_type(8)));
typedef _Float16 f16x8 __attribute__((ext_vector_type(8)));
typedef float  f32x4  __attribute__((ext_vector_type(4)));

#define GLB_AS(p) ((const __attribute__((address_space(1))) void*)(p))
#define LDS_AS(p) ((__attribute__((address_space(3))) void*)(p))

__device__ __forceinline__ void gll16(const void* g, void* l) {
    __builtin_amdgcn_global_load_lds(GLB_AS(g), LDS_AS(l), 16, 0, 0);
}

__device__ __forceinline__ double shfl_xor_dbl(double v, int m) {
    union { double d; int i[2]; } u;
    u.d = v;
    u.i[0] = __shfl_xor(u.i[0], m);
    u.i[1] = __shfl_xor(u.i[1], m);
    return u.d;
}

// ---------- f32 -> bf16 convert (plain weights) ----------
__global__ __launch_bounds__(256) void cvt_kernel(const float* __restrict__ in,
                                                  __hip_bfloat16* __restrict__ o) {
    const int i = blockIdx.x * 256 + threadIdx.x;
    const float4 v = ((const float4*)in)[i];
    __hip_bfloat16* p = o + (size_t)i * 4;
    p[0] = __float2bfloat16(v.x);
    p[1] = __float2bfloat16(v.y);
    p[2] = __float2bfloat16(v.z);
    p[3] = __float2bfloat16(v.w);
}

// ---------- qkv weight gather + fp16 hi/lo split (lo pre-scaled x1024) ----------
template <int OFS, bool HAS_LO>
__global__ __launch_bounds__(256) void cvt_split_kernel(const float* __restrict__ w,
                                                        _Float16* __restrict__ hi,
                                                        _Float16* __restrict__ lo) {
    const int j = blockIdx.x;
    const int src = (j >> 6) * 192 + OFS + (j & 63);
    const float4 v = ((const float4*)(w + (size_t)src * 1024))[threadIdx.x];
    _Float16 h0 = (_Float16)v.x, h1 = (_Float16)v.y, h2 = (_Float16)v.z, h3 = (_Float16)v.w;
    _Float16* hp = hi + (size_t)j * 1024 + threadIdx.x * 4;
    hp[0] = h0; hp[1] = h1; hp[2] = h2; hp[3] = h3;
    if (HAS_LO) {
        _Float16* lp = lo + (size_t)j * 1024 + threadIdx.x * 4;
        lp[0] = (_Float16)((v.x - (float)h0) * 1024.f);
        lp[1] = (_Float16)((v.y - (float)h1) * 1024.f);
        lp[2] = (_Float16)((v.z - (float)h2) * 1024.f);
        lp[3] = (_Float16)((v.w - (float)h3) * 1024.f);
    }
}

// ---------- LayerNorm f32 -> fp16 hi/lo (lo x1024), C=1024 ----------
__global__ __launch_bounds__(256) void ln_split_kernel(const float* __restrict__ x,
                                                       const float* __restrict__ w,
                                                       const float* __restrict__ b,
                                                       _Float16* __restrict__ yh,
                                                       _Float16* __restrict__ yl) {
    const int row = blockIdx.x;
    const int t = threadIdx.x;
    const float4 v = ((const float4*)(x + (size_t)row * 1024))[t];
    float s1 = v.x + v.y + v.z + v.w;
    float s2 = v.x * v.x + v.y * v.y + v.z * v.z + v.w * v.w;
#pragma unroll
    for (int off = 32; off; off >>= 1) {
        s1 += __shfl_xor(s1, off);
        s2 += __shfl_xor(s2, off);
    }
    __shared__ float red[8];
    const int wid = t >> 6, lane = t & 63;
    if (lane == 0) { red[wid] = s1; red[4 + wid] = s2; }
    __syncthreads();
    s1 = red[0] + red[1] + red[2] + red[3];
    s2 = red[4] + red[5] + red[6] + red[7];
    const float mu = s1 * (1.f / 1024.f);
    const float var = s2 * (1.f / 1024.f) - mu * mu;
    const float rs = rsqrtf(var + 1e-5f);
    const float4 wv = ((const float4*)w)[t];
    const float4 bv = ((const float4*)b)[t];
    float y[4] = {(v.x - mu) * rs * wv.x + bv.x, (v.y - mu) * rs * wv.y + bv.y,
                  (v.z - mu) * rs * wv.z + bv.z, (v.w - mu) * rs * wv.w + bv.w};
    _Float16* hp = yh + (size_t)row * 1024 + t * 4;
    _Float16* lp = yl + (size_t)row * 1024 + t * 4;
#pragma unroll
    for (int j = 0; j < 4; ++j) {
        _Float16 h = (_Float16)y[j];
        hp[j] = h;
        lp[j] = (_Float16)((y[j] - (float)h) * 1024.f);
    }
}

// ---------- LayerNorm f32 -> bf16 (LN2) ----------
__global__ __launch_bounds__(256) void ln_kernel(const float* __restrict__ x,
                                                 const float* __restrict__ w,
                                                 const float* __restrict__ b,
                                                 __hip_bfloat16* __restrict__ y) {
    const int row = blockIdx.x;
    const int t = threadIdx.x;
    const float4 v = ((const float4*)(x + (size_t)row * 1024))[t];
    float s1 = v.x + v.y + v.z + v.w;
    float s2 = v.x * v.x + v.y * v.y + v.z * v.z + v.w * v.w;
#pragma unroll
    for (int off = 32; off; off >>= 1) {
        s1 += __shfl_xor(s1, off);
        s2 += __shfl_xor(s2, off);
    }
    __shared__ float red[8];
    const int wid = t >> 6, lane = t & 63;
    if (lane == 0) { red[wid] = s1; red[4 + wid] = s2; }
    __syncthreads();
    s1 = red[0] + red[1] + red[2] + red[3];
    s2 = red[4] + red[5] + red[6] + red[7];
    const float mu = s1 * (1.f / 1024.f);
    const float var = s2 * (1.f / 1024.f) - mu * mu;
    const float rs = rsqrtf(var + 1e-5f);
    const float4 wv = ((const float4*)w)[t];
    const float4 bv = ((const float4*)b)[t];
    __hip_bfloat16* yp = y + (size_t)row * 1024 + t * 4;
    yp[0] = __float2bfloat16((v.x - mu) * rs * wv.x + bv.x);
    yp[1] = __float2bfloat16((v.y - mu) * rs * wv.y + bv.y);
    yp[2] = __float2bfloat16((v.z - mu) * rs * wv.z + bv.z);
    yp[3] = __float2bfloat16((v.w - mu) * rs * wv.w + bv.w);
}

// ---------- fp16x2 split GEMM (q/k) and fp16 GEMM (v). M=16384, N=1024, K=1024 ----------
// Pipelined double-buffered staging (counted vmcnt, raw barriers). Math order identical
// to the verified round-6 kernel (bit-exact numerics; den path is margin-critical).
template <int EPI>
__global__ __launch_bounds__(256) void gemm_f16(const _Float16* __restrict__ Ah,
                                                const _Float16* __restrict__ Al,
                                                const _Float16* __restrict__ Bh,
                                                const _Float16* __restrict__ Bl,
                                                const float* __restrict__ qkvb,
                                                _Float16* __restrict__ outp,
                                                const double* __restrict__ ksum_in,
                                                float* __restrict__ kpart,
                                                double* __restrict__ den_out) {
    constexpr int K = 1024;
    constexpr int NT = 32;                     // K/32
    // SM layout (bytes): AH[db]@db*8192, BH[db]@16384+db*8192, AL@32768+.., BL@49152+..
    __shared__ __align__(16) char SM[(EPI < 2) ? 65536 : 32768];
    __shared__ float kl[8][128];
    const int tid = threadIdx.x;
    const int wid = tid >> 6;
    const int lane = tid & 63;
    const int nwg = gridDim.x;                 // 1024, divisible by 8
    const int wg = (blockIdx.x & 7) * (nwg >> 3) + (blockIdx.x >> 3);
    const int bm = wg >> 3, bn = wg & 7;
    const int wr = (wid >> 1) * 64;
    const int wc = (wid & 1) * 64;
    const int l15 = lane & 15;
    const int lhi = lane >> 4;

    f32x4 acc0a[4][4] = {};
    f32x4 acc0b[4][4] = {};
    f32x4 acc1[4][4] = {};

    const int row0 = tid >> 2, colb0 = (tid & 3) * 16;
    constexpr size_t rowstride = (size_t)K * 2;
    const char* AhB = (const char*)(Ah + (size_t)(bm * 128) * K);
    const char* BhB = (const char*)(Bh + (size_t)(bn * 128) * K);
    const char* AlB = (const char*)(Al + (size_t)(bm * 128) * K);
    const char* BlB = (const char*)(Bl + (size_t)(bn * 128) * K);

    auto STAGE = [&](int db, int s) {
        const size_t o0 = (size_t)row0 * rowstride + (size_t)s * 64 + colb0;
        const size_t o1 = o0 + 64 * rowstride;
        char* AH = SM + db * 8192;
        char* BH = SM + 16384 + db * 8192;
        gll16(AhB + o0, AH + wid * 1024);
        gll16(AhB + o1, AH + 4096 + wid * 1024);
        gll16(BhB + o0, BH + wid * 1024);
        gll16(BhB + o1, BH + 4096 + wid * 1024);
        if (EPI < 2) {
            char* AL = SM + 32768 + db * 8192;
            char* BL = SM + 49152 + db * 8192;
            gll16(AlB + o0, AL + wid * 1024);
            gll16(AlB + o1, AL + 4096 + wid * 1024);
            gll16(BlB + o0, BL + wid * 1024);
            gll16(BlB + o1, BL + 4096 + wid * 1024);
        }
    };
    auto COMPUTE = [&](int db, f32x4 (&accH)[4][4]) {
        const _Float16* AH = (const _Float16*)(SM + db * 8192);
        const _Float16* BH = (const _Float16*)(SM + 16384 + db * 8192);
        const _Float16* AL = (const _Float16*)(SM + 32768 + db * 8192);
        const _Float16* BL = (const _Float16*)(SM + 49152 + db * 8192);
        f16x8 ah[4], bh[4], al[4], bl[4];
#pragma unroll
        for (int m = 0; m < 4; ++m) {
            ah[m] = *(const f16x8*)(AH + (wr + m * 16 + l15) * 32 + lhi * 8);
            if (EPI < 2) al[m] = *(const f16x8*)(AL + (wr + m * 16 + l15) * 32 + lhi * 8);
        }
#pragma unroll
        for (int n = 0; n < 4; ++n) {
            bh[n] = *(const f16x8*)(BH + (wc + n * 16 + l15) * 32 + lhi * 8);
            if (EPI < 2) bl[n] = *(const f16x8*)(BL + (wc + n * 16 + l15) * 32 + lhi * 8);
        }
#pragma unroll
        for (int m = 0; m < 4; ++m)
#pragma unroll
            for (int n = 0; n < 4; ++n) {
                accH[m][n] = __builtin_amdgcn_mfma_f32_16x16x32_f16(ah[m], bh[n], accH[m][n], 0, 0, 0);
                if (EPI < 2) {
                    acc1[m][n] = __builtin_amdgcn_mfma_f32_16x16x32_f16(ah[m], bl[n], acc1[m][n], 0, 0, 0);
                    acc1[m][n] = __builtin_amdgcn_mfma_f32_16x16x32_f16(al[m], bh[n], acc1[m][n], 0, 0, 0);
                }
            }
    };

    STAGE(0, 0);
    for (int s = 0; s < NT - 1; ++s) {
        const int cur = s & 1;
        STAGE(cur ^ 1, s + 1);
        if (EPI < 2) asm volatile("s_waitcnt vmcnt(8)" ::: "memory");
        else         asm volatile("s_waitcnt vmcnt(4)" ::: "memory");
        __builtin_amdgcn_s_barrier();
        __builtin_amdgcn_sched_barrier(0);
        if (EPI == 0 && s >= 16) COMPUTE(cur, acc0b);
        else                     COMPUTE(cur, acc0a);
        __builtin_amdgcn_sched_barrier(0);
        __builtin_amdgcn_s_barrier();
    }
    asm volatile("s_waitcnt vmcnt(0)" ::: "memory");
    __builtin_amdgcn_s_barrier();
    __builtin_amdgcn_sched_barrier(0);
    if (EPI == 0) COMPUTE((NT - 1) & 1, acc0b);
    else          COMPUTE((NT - 1) & 1, acc0a);

    // epilogue. C/D: col = lane&15, row = (lane>>4)*4 + i  (identical to round-6)
    const int rbase = bm * 128 + wr + lhi * 4;
    const int j0 = bn * 128 + wc + l15;
    const int hh = (bn * 128 + wc) >> 6;
    const int bofs = (EPI == 0) ? 0 : (EPI == 1) ? 64 : 128;
    const int bb = (bm * 128) >> 12;
    const int kbase = bb * 1024 + hh * 64;

    double ks[4];
    if (EPI == 0) {
#pragma unroll
        for (int n = 0; n < 4; ++n) ks[n] = ksum_in[kbase + n * 16 + l15];
    }
    double kcol[4] = {};

#pragma unroll
    for (int m = 0; m < 4; ++m) {
#pragma unroll
        for (int i = 0; i < 4; ++i) {
            const int gr = rbase + m * 16 + i;
            double denv = 0.0;
#pragma unroll
            for (int n = 0; n < 4; ++n) {
                double qd = (double)acc0a[m][n][i] + (double)acc0b[m][n][i];
                if (EPI < 2) qd += (double)acc1[m][n][i] * (1.0 / 1024.0);
                qd += (double)qkvb[hh * 192 + bofs + n * 16 + l15];
                if (EPI < 2) {
                    const double sd = qd / (1.0 + exp(-qd));
                    outp[(size_t)gr * 1024 + j0 + n * 16] = (_Float16)(float)sd;
                    if (EPI == 0) denv += sd * ks[n];
                    if (EPI == 1) kcol[n] += sd;
                } else {
                    outp[(size_t)gr * 1024 + j0 + n * 16] = (_Float16)(float)qd;
                }
            }
            if (EPI == 0) {
                denv += shfl_xor_dbl(denv, 1);
                denv += shfl_xor_dbl(denv, 2);
                denv += shfl_xor_dbl(denv, 4);
                denv += shfl_xor_dbl(denv, 8);
                if (l15 == 0) den_out[(size_t)gr * 16 + hh] = denv;
            }
        }
    }
    if (EPI == 1) {
        const int part = (wr >> 6) * 4 + lhi;
#pragma unroll
        for (int n = 0; n < 4; ++n) kl[part][wc + n * 16 + l15] = (float)kcol[n];
        __syncthreads();
        if (tid < 128) {
            double s = 0.0;
#pragma unroll
            for (int p = 0; p < 8; ++p) s += (double)kl[p][tid];
            kpart[(size_t)bm * 1024 + bn * 128 + tid] = (float)s;
        }
    }
}

// ---------- ksum reduce: KSUM[b][col] = sum_{j<32} KPART[b*32+j][col], f64 ----------
__global__ __launch_bounds__(256) void ksum_reduce_kernel(const float* __restrict__ kpart,
                                                          double* __restrict__ ksum) {
    const int idx = blockIdx.x * 256 + threadIdx.x;   // [0,4096)
    const int b = idx >> 10, col = idx & 1023;
    double acc = 0.0;
    for (int j = 0; j < 32; ++j) acc += (double)kpart[(size_t)(b * 32 + j) * 1024 + col];
    ksum[idx] = acc;
}

// ---------- bf16 GEMM, pipelined dbuf: C = epi(A * Bt^T + bias) ----------
// EPI 1: +resid (f32), f32 out ; EPI 2: gelu exact, bf16 out
template <int EPI, int N, int K>
__global__ __launch_bounds__(256) void gemm_bt(const __hip_bfloat16* __restrict__ A,
                                               const __hip_bfloat16* __restrict__ Bt,
                                               const float* __restrict__ bias,
                                               const float* __restrict__ resid,
                                               void* __restrict__ outp) {
    constexpr int NT = K / 32;
    constexpr int NBN = N / 128;
    __shared__ __align__(16) char SM[2 * 16384];   // [db][As 8K | Bs 8K]
    const int tid = threadIdx.x;
    const int wid = tid >> 6;
    const int lane = tid & 63;
    const int nwg = gridDim.x;                     // divisible by 8
    const int wg = (blockIdx.x & 7) * (nwg >> 3) + (blockIdx.x >> 3);
    const int bm = wg / NBN, bn = wg % NBN;
    const int wr = (wid >> 1) * 64;
    const int wc = (wid & 1) * 64;
    const int l15 = lane & 15;
    const int lhi = lane >> 4;

    f32x4 acc[4][4] = {};

    const int row0 = tid >> 2, colb0 = (tid & 3) * 16;
    const char* Abase = (const char*)(A + (size_t)(bm * 128) * K);
    const char* Bbase = (const char*)(Bt + (size_t)(bn * 128) * K);
    constexpr size_t rowstride = (size_t)K * 2;

    auto STAGE = [&](int db, int s) {
        const size_t o0 = (size_t)row0 * rowstride + (size_t)s * 64 + colb0;
        const size_t o1 = o0 + 64 * rowstride;
        char* As = SM + db * 16384;
        char* Bs = As + 8192;
        gll16(Abase + o0, As + wid * 1024);
        gll16(Abase + o1, As + 4096 + wid * 1024);
        gll16(Bbase + o0, Bs + wid * 1024);
        gll16(Bbase + o1, Bs + 4096 + wid * 1024);
    };
    auto COMPUTE = [&](int db) {
        const __hip_bfloat16* As = (const __hip_bfloat16*)(SM + db * 16384);
        const __hip_bfloat16* Bs = As + 4096;
        bf16x8 af[4], bf4[4];
#pragma unroll
        for (int m = 0; m < 4; ++m)
            af[m] = *(const bf16x8*)(As + (wr + m * 16 + l15) * 32 + lhi * 8);
#pragma unroll
        for (int n = 0; n < 4; ++n)
            bf4[n] = *(const bf16x8*)(Bs + (wc + n * 16 + l15) * 32 + lhi * 8);
#pragma unroll
        for (int m = 0; m < 4; ++m)
#pragma unroll
            for (int n = 0; n < 4; ++n)
                acc[m][n] = __builtin_amdgcn_mfma_f32_16x16x32_bf16(af[m], bf4[n], acc[m][n], 0, 0, 0);
    };

    STAGE(0, 0);
    for (int s = 0; s < NT - 1; ++s) {
        const int cur = s & 1;
        STAGE(cur ^ 1, s + 1);
        asm volatile("s_waitcnt vmcnt(4)" ::: "memory");
        __builtin_amdgcn_s_barrier();
        __builtin_amdgcn_sched_barrier(0);
        COMPUTE(cur);
        __builtin_amdgcn_sched_barrier(0);
        __builtin_amdgcn_s_barrier();
    }
    asm volatile("s_waitcnt vmcnt(0)" ::: "memory");
    __builtin_amdgcn_s_barrier();
    __builtin_amdgcn_sched_barrier(0);
    COMPUTE((NT - 1) & 1);

    const int rbase = bm * 128 + wr + lhi * 4;
    const int cbase = bn * 128 + wc + l15;
#pragma unroll
    for (int n = 0; n < 4; ++n) {
        const int gc = cbase + n * 16;
        const float bv = bias[gc];
#pragma unroll
        for (int m = 0; m < 4; ++m) {
#pragma unroll
            for (int i = 0; i < 4; ++i) {
                const int gr = rbase + m * 16 + i;
                const size_t o = (size_t)gr * N + gc;
                float v = acc[m][n][i] + bv;
                if (EPI == 1) {
                    ((float*)outp)[o] = v + resid[o];
                } else {
                    v = 0.5f * v * (1.f + erff(v * 0.70710678118f));
                    ((__hip_bfloat16*)outp)[o] = __float2bfloat16(v);
                }
            }
        }
    }
}

// ---------- attention state partials: s8[split][bh][d][e] = sum_n k*v over split ----------
__global__ __launch_bounds__(256) void attn_state_kernel(const _Float16* __restrict__ Kf,
                                                         const _Float16* __restrict__ Vf,
                                                         float* __restrict__ s8) {
    const int bh = blockIdx.x;
    const int b = bh >> 4, h = bh & 15;
    const int n0 = blockIdx.y * 512;
    __shared__ float klds[64][64];
    __shared__ float vlds[64][64];
    const int t = threadIdx.x;
    const int r = t >> 2, cc = (t & 3) * 16;
    const int d = t >> 2, e0 = (t & 3) * 16;
    float s[16] = {};

    for (int c = 0; c < 512; c += 64) {
        const size_t m = (size_t)b * 4096 + n0 + c + r;
        const _Float16* kb = Kf + m * 1024 + h * 64;
        const _Float16* vb = Vf + m * 1024 + h * 64;
        const f16x8 k0 = *(const f16x8*)(kb + cc);
        const f16x8 k1 = *(const f16x8*)(kb + cc + 8);
        const f16x8 v0 = *(const f16x8*)(vb + cc);
        const f16x8 v1 = *(const f16x8*)(vb + cc + 8);
        __syncthreads();
#pragma unroll
        for (int j = 0; j < 8; ++j) {
            klds[r][cc + j]     = (float)k0[j];
            klds[r][cc + 8 + j] = (float)k1[j];
            vlds[r][cc + j]     = (float)v0[j];
            vlds[r][cc + 8 + j] = (float)v1[j];
        }
        __syncthreads();
#pragma unroll 8
        for (int n = 0; n < 64; ++n) {
            const float kk = klds[n][d];
            const float4* vp = (const float4*)&vlds[n][e0];
            const float4 a0 = vp[0], a1 = vp[1], a2 = vp[2], a3 = vp[3];
            s[0]  += kk * a0.x; s[1]  += kk * a0.y; s[2]  += kk * a0.z; s[3]  += kk * a0.w;
            s[4]  += kk * a1.x; s[5]  += kk * a1.y; s[6]  += kk * a1.z; s[7]  += kk * a1.w;
            s[8]  += kk * a2.x; s[9]  += kk * a2.y; s[10] += kk * a2.z; s[11] += kk * a2.w;
            s[12] += kk * a3.x; s[13] += kk * a3.y; s[14] += kk * a3.z; s[15] += kk * a3.w;
        }
    }
    float* sp = s8 + (((size_t)blockIdx.y * 64 + bh) * 64 + d) * 64 + e0;
#pragma unroll
    for (int j = 0; j < 16; ++j) sp[j] = s[j];
}

// ---------- state reduce ----------
__global__ __launch_bounds__(256) void state_reduce_kernel(const float* __restrict__ s8,
                                                           float* __restrict__ state) {
    const int idx = blockIdx.x * 256 + threadIdx.x;
    float a = 0.f;
#pragma unroll
    for (int j = 0; j < 8; ++j) a += s8[(size_t)j * 262144 + idx];
    state[idx] = a;
}

// ---------- attention out ----------
__global__ __launch_bounds__(256) void attn_out_kernel(const _Float16* __restrict__ Qf,
                                                       const float* __restrict__ state,
                                                       const double* __restrict__ den,
                                                       __hip_bfloat16* __restrict__ aout) {
    const int bh = blockIdx.x;
    const int b = bh >> 4, h = bh & 15;
    const int n0 = blockIdx.y * 64;
    __shared__ float slds[64][64];
    __shared__ float qlds[64][65];
    const int t = threadIdx.x;
    {
        const float4* sp = (const float4*)(state + (size_t)bh * 4096);
        float4* dp = (float4*)&slds[0][0];
#pragma unroll
        for (int i = 0; i < 4; ++i) dp[i * 256 + t] = sp[i * 256 + t];
    }
    {
        const int r = t >> 2, cc = (t & 3) * 16;
        const size_t m = (size_t)b * 4096 + n0 + r;
        const _Float16* qb = Qf + m * 1024 + h * 64;
        const f16x8 q0 = *(const f16x8*)(qb + cc);
        const f16x8 q1 = *(const f16x8*)(qb + cc + 8);
#pragma unroll
        for (int j = 0; j < 8; ++j) {
            qlds[r][cc + j]     = (float)q0[j];
            qlds[r][cc + 8 + j] = (float)q1[j];
        }
    }
    __syncthreads();
    const int r = t >> 2, e0 = (t & 3) * 16;
    const size_t mrow = (size_t)b * 4096 + n0 + r;
    float o[16] = {};
#pragma unroll 8
    for (int dd = 0; dd < 64; ++dd) {
        const float qv = qlds[r][dd];
        const float4* sp4 = (const float4*)&slds[dd][e0];
        const float4 a0 = sp4[0], a1 = sp4[1], a2 = sp4[2], a3 = sp4[3];
        o[0]  += qv * a0.x; o[1]  += qv * a0.y; o[2]  += qv * a0.z; o[3]  += qv * a0.w;
        o[4]  += qv * a1.x; o[5]  += qv * a1.y; o[6]  += qv * a1.z; o[7]  += qv * a1.w;
        o[8]  += qv * a2.x; o[9]  += qv * a2.y; o[10] += qv * a2.z; o[11] += qv * a2.w;
        o[12] += qv * a3.x; o[13] += qv * a3.y; o[14] += qv * a3.z; o[15] += qv * a3.w;
    }
    const float inv = (float)(1.0 / (den[mrow * 16 + h] + 1e-6));
    __hip_bfloat16* op = aout + mrow * 1024 + h * 64 + e0;
#pragma unroll
    for (int j = 0; j < 16; ++j) op[j] = __float2bfloat16(o[j] * inv);
}

// ---------- launch ----------
extern "C" void kernel_launch(void* const* d_in, const int* in_sizes, int n_in,
                              void* d_out, int out_size, void* d_ws, size_t ws_size,
                              hipStream_t stream) {
    const float* x     = (const float*)d_in[0];
    const float* ln1_w = (const float*)d_in[1];
    const float* ln1_b = (const float*)d_in[2];
    const float* ln2_w = (const float*)d_in[3];
    const float* ln2_b = (const float*)d_in[4];
    const float* qkv_w = (const float*)d_in[5];
    const float* qkv_b = (const float*)d_in[6];
    const float* out_w = (const float*)d_in[7];
    const float* out_b = (const float*)d_in[8];
    const float* fc1_w = (const float*)d_in[9];
    const float* fc1_b = (const float*)d_in[10];
    const float* fc2_w = (const float*)d_in[11];
    const float* fc2_b = (const float*)d_in[12];
    float* out = (float*)d_out;

    char* ws = (char*)d_ws;
    _Float16* Wqh = (_Float16*)(ws + 0);
    _Float16* Wql = (_Float16*)(ws + 2097152);
    _Float16* Wkh = (_Float16*)(ws + 4194304);
    _Float16* Wkl = (_Float16*)(ws + 6291456);
    _Float16* Wvh = (_Float16*)(ws + 8388608);
    __hip_bfloat16* Wo = (__hip_bfloat16*)(ws + 10485760);
    __hip_bfloat16* W1 = (__hip_bfloat16*)(ws + 12582912);
    __hip_bfloat16* W2 = (__hip_bfloat16*)(ws + 20971520);
    _Float16* XH = (_Float16*)(ws + 29360128);
    _Float16* XL = (_Float16*)(ws + 62914560);
    _Float16* QF = (_Float16*)(ws + 96468992);
    _Float16* KF = (_Float16*)(ws + 130023424);
    _Float16* VF = (_Float16*)(ws + 163577856);
    double* DEN  = (double*)(ws + 197132288);
    float* KPART = (float*)(ws + 199229440);
    double* KSUM = (double*)(ws + 199753728);
    float* STATE = (float*)(ws + 199786496);
    float* STATE8 = (float*)XH;                 // 8 MB overlay on dead XH
    __hip_bfloat16* AO   = (__hip_bfloat16*)XL;
    __hip_bfloat16* Hbuf = (__hip_bfloat16*)XL;
    __hip_bfloat16* XN2  = (__hip_bfloat16*)XH;

    cvt_split_kernel<0, true><<<1024, 256, 0, stream>>>(qkv_w, Wqh, Wql);
    cvt_split_kernel<64, true><<<1024, 256, 0, stream>>>(qkv_w, Wkh, Wkl);
    cvt_split_kernel<128, false><<<1024, 256, 0, stream>>>(qkv_w, Wvh, nullptr);
    cvt_kernel<<<1024, 256, 0, stream>>>(out_w, Wo);
    cvt_kernel<<<4096, 256, 0, stream>>>(fc1_w, W1);
    cvt_kernel<<<4096, 256, 0, stream>>>(fc2_w, W2);

    ln_split_kernel<<<16384, 256, 0, stream>>>(x, ln1_w, ln1_b, XH, XL);

    // k (kpart) -> ksum f64 -> q (den) ; v independent
    gemm_f16<1><<<1024, 256, 0, stream>>>(XH, XL, Wkh, Wkl, qkv_b, KF, nullptr, KPART, nullptr);
    ksum_reduce_kernel<<<16, 256, 0, stream>>>(KPART, KSUM);
    gemm_f16<0><<<1024, 256, 0, stream>>>(XH, XL, Wqh, Wql, qkv_b, QF, KSUM, nullptr, DEN);
    gemm_f16<2><<<1024, 256, 0, stream>>>(XH, nullptr, Wvh, nullptr, qkv_b, VF, nullptr, nullptr, nullptr);

    attn_state_kernel<<<dim3(64, 8), 256, 0, stream>>>(KF, VF, STATE8);
    state_reduce_kernel<<<1024, 256, 0, stream>>>(STATE8, STATE);
    attn_out_kernel<<<dim3(64, 64), 256, 0, stream>>>(QF, STATE, DEN, AO);

    // out proj + residual -> x2 (f32, in d_out)
    gemm_bt<1, 1024, 1024><<<1024, 256, 0, stream>>>(AO, Wo, out_b, x, out);
    // LN2
    ln_kernel<<<16384, 256, 0, stream>>>(out, ln2_w, ln2_b, XN2);
    // fc1 + gelu
    gemm_bt<2, 4096, 1024><<<4096, 256, 0, stream>>>(XN2, W1, fc1_b, nullptr, Hbuf);
    // fc2 + bias + residual -> final out
    gemm_bt<1, 1024, 4096><<<1024, 256, 0, stream>>>(Hbuf, W2, fc2_b, out, out);
}

// Round 10
// 1206.938 us; speedup vs baseline: 1.2047x; 1.0578x over previous
//
#include <hip/hip_runtime.h>
#include <hip/hip_bf16.h>
#include <math.h>

// ---------- types ----------
typedef __bf16 bf16x8 __attribute__((ext_vector_type(8)));
typedef _Float16 f16x8 __attribute__((ext_vector_type(8)));
typedef float  f32x4  __attribute__((ext_vector_type(4)));

#define GLB_AS(p) ((const __attribute__((address_space(1))) void*)(p))
#define LDS_AS(p) ((__attribute__((address_space(3))) void*)(p))

__device__ __forceinline__ void gll16(const void* g, void* l) {
    __builtin_amdgcn_global_load_lds(GLB_AS(g), LDS_AS(l), 16, 0, 0);
}

__device__ __forceinline__ double shfl_xor_dbl(double v, int m) {
    union { double d; int i[2]; } u;
    u.d = v;
    u.i[0] = __shfl_xor(u.i[0], m);
    u.i[1] = __shfl_xor(u.i[1], m);
    return u.d;
}

// ---------- f32 -> bf16 convert (plain weights) ----------
__global__ __launch_bounds__(256) void cvt_kernel(const float* __restrict__ in,
                                                  __hip_bfloat16* __restrict__ o) {
    const int i = blockIdx.x * 256 + threadIdx.x;
    const float4 v = ((const float4*)in)[i];
    __hip_bfloat16* p = o + (size_t)i * 4;
    p[0] = __float2bfloat16(v.x);
    p[1] = __float2bfloat16(v.y);
    p[2] = __float2bfloat16(v.z);
    p[3] = __float2bfloat16(v.w);
}

// ---------- qkv weight gather + fp16 hi/lo split (lo pre-scaled x1024) ----------
template <int OFS, bool HAS_LO>
__global__ __launch_bounds__(256) void cvt_split_kernel(const float* __restrict__ w,
                                                        _Float16* __restrict__ hi,
                                                        _Float16* __restrict__ lo) {
    const int j = blockIdx.x;
    const int src = (j >> 6) * 192 + OFS + (j & 63);
    const float4 v = ((const float4*)(w + (size_t)src * 1024))[threadIdx.x];
    _Float16 h0 = (_Float16)v.x, h1 = (_Float16)v.y, h2 = (_Float16)v.z, h3 = (_Float16)v.w;
    _Float16* hp = hi + (size_t)j * 1024 + threadIdx.x * 4;
    hp[0] = h0; hp[1] = h1; hp[2] = h2; hp[3] = h3;
    if (HAS_LO) {
        _Float16* lp = lo + (size_t)j * 1024 + threadIdx.x * 4;
        lp[0] = (_Float16)((v.x - (float)h0) * 1024.f);
        lp[1] = (_Float16)((v.y - (float)h1) * 1024.f);
        lp[2] = (_Float16)((v.z - (float)h2) * 1024.f);
        lp[3] = (_Float16)((v.w - (float)h3) * 1024.f);
    }
}

// ---------- LayerNorm f32 -> fp16 hi/lo (lo x1024), C=1024 ----------
__global__ __launch_bounds__(256) void ln_split_kernel(const float* __restrict__ x,
                                                       const float* __restrict__ w,
                                                       const float* __restrict__ b,
                                                       _Float16* __restrict__ yh,
                                                       _Float16* __restrict__ yl) {
    const int row = blockIdx.x;
    const int t = threadIdx.x;
    const float4 v = ((const float4*)(x + (size_t)row * 1024))[t];
    float s1 = v.x + v.y + v.z + v.w;
    float s2 = v.x * v.x + v.y * v.y + v.z * v.z + v.w * v.w;
#pragma unroll
    for (int off = 32; off; off >>= 1) {
        s1 += __shfl_xor(s1, off);
        s2 += __shfl_xor(s2, off);
    }
    __shared__ float red[8];
    const int wid = t >> 6, lane = t & 63;
    if (lane == 0) { red[wid] = s1; red[4 + wid] = s2; }
    __syncthreads();
    s1 = red[0] + red[1] + red[2] + red[3];
    s2 = red[4] + red[5] + red[6] + red[7];
    const float mu = s1 * (1.f / 1024.f);
    const float var = s2 * (1.f / 1024.f) - mu * mu;
    const float rs = rsqrtf(var + 1e-5f);
    const float4 wv = ((const float4*)w)[t];
    const float4 bv = ((const float4*)b)[t];
    float y[4] = {(v.x - mu) * rs * wv.x + bv.x, (v.y - mu) * rs * wv.y + bv.y,
                  (v.z - mu) * rs * wv.z + bv.z, (v.w - mu) * rs * wv.w + bv.w};
    _Float16* hp = yh + (size_t)row * 1024 + t * 4;
    _Float16* lp = yl + (size_t)row * 1024 + t * 4;
#pragma unroll
    for (int j = 0; j < 4; ++j) {
        _Float16 h = (_Float16)y[j];
        hp[j] = h;
        lp[j] = (_Float16)((y[j] - (float)h) * 1024.f);
    }
}

// ---------- LayerNorm f32 -> bf16 (LN2) ----------
__global__ __launch_bounds__(256) void ln_kernel(const float* __restrict__ x,
                                                 const float* __restrict__ w,
                                                 const float* __restrict__ b,
                                                 __hip_bfloat16* __restrict__ y) {
    const int row = blockIdx.x;
    const int t = threadIdx.x;
    const float4 v = ((const float4*)(x + (size_t)row * 1024))[t];
    float s1 = v.x + v.y + v.z + v.w;
    float s2 = v.x * v.x + v.y * v.y + v.z * v.z + v.w * v.w;
#pragma unroll
    for (int off = 32; off; off >>= 1) {
        s1 += __shfl_xor(s1, off);
        s2 += __shfl_xor(s2, off);
    }
    __shared__ float red[8];
    const int wid = t >> 6, lane = t & 63;
    if (lane == 0) { red[wid] = s1; red[4 + wid] = s2; }
    __syncthreads();
    s1 = red[0] + red[1] + red[2] + red[3];
    s2 = red[4] + red[5] + red[6] + red[7];
    const float mu = s1 * (1.f / 1024.f);
    const float var = s2 * (1.f / 1024.f) - mu * mu;
    const float rs = rsqrtf(var + 1e-5f);
    const float4 wv = ((const float4*)w)[t];
    const float4 bv = ((const float4*)b)[t];
    __hip_bfloat16* yp = y + (size_t)row * 1024 + t * 4;
    yp[0] = __float2bfloat16((v.x - mu) * rs * wv.x + bv.x);
    yp[1] = __float2bfloat16((v.y - mu) * rs * wv.y + bv.y);
    yp[2] = __float2bfloat16((v.z - mu) * rs * wv.z + bv.z);
    yp[3] = __float2bfloat16((v.w - mu) * rs * wv.w + bv.w);
}

// ---------- fp16x2 split GEMM (q/k) and fp16 GEMM (v). M=16384, N=1024, K=1024 ----------
// Pipelined double-buffered staging. NUMERICS FROZEN (bit-identical to round-7/9 pass).
template <int EPI>
__global__ __launch_bounds__(256) void gemm_f16(const _Float16* __restrict__ Ah,
                                                const _Float16* __restrict__ Al,
                                                const _Float16* __restrict__ Bh,
                                                const _Float16* __restrict__ Bl,
                                                const float* __restrict__ qkvb,
                                                _Float16* __restrict__ outp,
                                                const double* __restrict__ ksum_in,
                                                float* __restrict__ kpart,
                                                double* __restrict__ den_out) {
    constexpr int K = 1024;
    constexpr int NT = 32;                     // K/32
    __shared__ __align__(16) char SM[(EPI < 2) ? 65536 : 32768];
    __shared__ float kl[(EPI == 1) ? 8 : 1][128];
    const int tid = threadIdx.x;
    const int wid = tid >> 6;
    const int lane = tid & 63;
    const int nwg = gridDim.x;                 // 1024, divisible by 8
    const int wg = (blockIdx.x & 7) * (nwg >> 3) + (blockIdx.x >> 3);
    const int bm = wg >> 3, bn = wg & 7;
    const int wr = (wid >> 1) * 64;
    const int wc = (wid & 1) * 64;
    const int l15 = lane & 15;
    const int lhi = lane >> 4;

    f32x4 acc0a[4][4] = {};
    f32x4 acc0b[4][4] = {};
    f32x4 acc1[4][4] = {};

    const int row0 = tid >> 2, colb0 = (tid & 3) * 16;
    constexpr size_t rowstride = (size_t)K * 2;
    const char* AhB = (const char*)(Ah + (size_t)(bm * 128) * K);
    const char* BhB = (const char*)(Bh + (size_t)(bn * 128) * K);
    const char* AlB = (const char*)(Al + (size_t)(bm * 128) * K);
    const char* BlB = (const char*)(Bl + (size_t)(bn * 128) * K);

    auto STAGE = [&](int db, int s) {
        const size_t o0 = (size_t)row0 * rowstride + (size_t)s * 64 + colb0;
        const size_t o1 = o0 + 64 * rowstride;
        char* AH = SM + db * 8192;
        char* BH = SM + 16384 + db * 8192;
        gll16(AhB + o0, AH + wid * 1024);
        gll16(AhB + o1, AH + 4096 + wid * 1024);
        gll16(BhB + o0, BH + wid * 1024);
        gll16(BhB + o1, BH + 4096 + wid * 1024);
        if (EPI < 2) {
            char* AL = SM + 32768 + db * 8192;
            char* BL = SM + 49152 + db * 8192;
            gll16(AlB + o0, AL + wid * 1024);
            gll16(AlB + o1, AL + 4096 + wid * 1024);
            gll16(BlB + o0, BL + wid * 1024);
            gll16(BlB + o1, BL + 4096 + wid * 1024);
        }
    };
    auto COMPUTE = [&](int db, f32x4 (&accH)[4][4]) {
        const _Float16* AH = (const _Float16*)(SM + db * 8192);
        const _Float16* BH = (const _Float16*)(SM + 16384 + db * 8192);
        const _Float16* AL = (const _Float16*)(SM + 32768 + db * 8192);
        const _Float16* BL = (const _Float16*)(SM + 49152 + db * 8192);
        f16x8 ah[4], bh[4], al[4], bl[4];
#pragma unroll
        for (int m = 0; m < 4; ++m) {
            ah[m] = *(const f16x8*)(AH + (wr + m * 16 + l15) * 32 + lhi * 8);
            if (EPI < 2) al[m] = *(const f16x8*)(AL + (wr + m * 16 + l15) * 32 + lhi * 8);
        }
#pragma unroll
        for (int n = 0; n < 4; ++n) {
            bh[n] = *(const f16x8*)(BH + (wc + n * 16 + l15) * 32 + lhi * 8);
            if (EPI < 2) bl[n] = *(const f16x8*)(BL + (wc + n * 16 + l15) * 32 + lhi * 8);
        }
#pragma unroll
        for (int m = 0; m < 4; ++m)
#pragma unroll
            for (int n = 0; n < 4; ++n) {
                accH[m][n] = __builtin_amdgcn_mfma_f32_16x16x32_f16(ah[m], bh[n], accH[m][n], 0, 0, 0);
                if (EPI < 2) {
                    acc1[m][n] = __builtin_amdgcn_mfma_f32_16x16x32_f16(ah[m], bl[n], acc1[m][n], 0, 0, 0);
                    acc1[m][n] = __builtin_amdgcn_mfma_f32_16x16x32_f16(al[m], bh[n], acc1[m][n], 0, 0, 0);
                }
            }
    };

    STAGE(0, 0);
    for (int s = 0; s < NT - 1; ++s) {
        const int cur = s & 1;
        STAGE(cur ^ 1, s + 1);
        if (EPI < 2) asm volatile("s_waitcnt vmcnt(8)" ::: "memory");
        else         asm volatile("s_waitcnt vmcnt(4)" ::: "memory");
        __builtin_amdgcn_s_barrier();
        __builtin_amdgcn_sched_barrier(0);
        if (EPI == 0 && s >= 16) COMPUTE(cur, acc0b);
        else                     COMPUTE(cur, acc0a);
        __builtin_amdgcn_sched_barrier(0);
        __builtin_amdgcn_s_barrier();
    }
    asm volatile("s_waitcnt vmcnt(0)" ::: "memory");
    __builtin_amdgcn_s_barrier();
    __builtin_amdgcn_sched_barrier(0);
    if (EPI == 0) COMPUTE((NT - 1) & 1, acc0b);
    else          COMPUTE((NT - 1) & 1, acc0a);

    // epilogue. C/D: col = lane&15, row = (lane>>4)*4 + i  (identical numerics)
    const int rbase = bm * 128 + wr + lhi * 4;
    const int j0 = bn * 128 + wc + l15;
    const int hh = (bn * 128 + wc) >> 6;
    const int bofs = (EPI == 0) ? 0 : (EPI == 1) ? 64 : 128;
    const int bb = (bm * 128) >> 12;
    const int kbase = bb * 1024 + hh * 64;

    double ks[4];
    if (EPI == 0) {
#pragma unroll
        for (int n = 0; n < 4; ++n) ks[n] = ksum_in[kbase + n * 16 + l15];
    }
    double kcol[4] = {};

#pragma unroll
    for (int m = 0; m < 4; ++m) {
#pragma unroll
        for (int i = 0; i < 4; ++i) {
            const int gr = rbase + m * 16 + i;
            double denv = 0.0;
#pragma unroll
            for (int n = 0; n < 4; ++n) {
                double qd = (double)acc0a[m][n][i] + (double)acc0b[m][n][i];
                if (EPI < 2) qd += (double)acc1[m][n][i] * (1.0 / 1024.0);
                qd += (double)qkvb[hh * 192 + bofs + n * 16 + l15];
                if (EPI < 2) {
                    const double sd = qd / (1.0 + exp(-qd));
                    outp[(size_t)gr * 1024 + j0 + n * 16] = (_Float16)(float)sd;
                    if (EPI == 0) denv += sd * ks[n];
                    if (EPI == 1) kcol[n] += sd;
                } else {
                    outp[(size_t)gr * 1024 + j0 + n * 16] = (_Float16)(float)qd;
                }
            }
            if (EPI == 0) {
                denv += shfl_xor_dbl(denv, 1);
                denv += shfl_xor_dbl(denv, 2);
                denv += shfl_xor_dbl(denv, 4);
                denv += shfl_xor_dbl(denv, 8);
                if (l15 == 0) den_out[(size_t)gr * 16 + hh] = denv;
            }
        }
    }
    if (EPI == 1) {
        const int part = (wr >> 6) * 4 + lhi;
#pragma unroll
        for (int n = 0; n < 4; ++n) kl[part][wc + n * 16 + l15] = (float)kcol[n];
        __syncthreads();
        if (tid < 128) {
            double s = 0.0;
#pragma unroll
            for (int p = 0; p < 8; ++p) s += (double)kl[p][tid];
            kpart[(size_t)bm * 1024 + bn * 128 + tid] = (float)s;
        }
    }
}

// ---------- ksum reduce: KSUM[b][col] = sum_{j<32} KPART[b*32+j][col], f64 ----------
__global__ __launch_bounds__(256) void ksum_reduce_kernel(const float* __restrict__ kpart,
                                                          double* __restrict__ ksum) {
    const int idx = blockIdx.x * 256 + threadIdx.x;   // [0,4096)
    const int b = idx >> 10, col = idx & 1023;
    double acc = 0.0;
    for (int j = 0; j < 32; ++j) acc += (double)kpart[(size_t)(b * 32 + j) * 1024 + col];
    ksum[idx] = acc;
}

// ---------- bf16 GEMM, 256x128 tile, 512 thr, pipelined dbuf ----------
// EPI 1: +resid (f32), f32 out ; EPI 2: gelu exact, bf16 out
// Per-output MFMA chain identical to 128x128 version -> bit-identical results.
template <int EPI, int N, int K>
__global__ __launch_bounds__(512, 4) void gemm_bt(const __hip_bfloat16* __restrict__ A,
                                                  const __hip_bfloat16* __restrict__ Bt,
                                                  const float* __restrict__ bias,
                                                  const float* __restrict__ resid,
                                                  void* __restrict__ outp) {
    constexpr int NT = K / 32;
    constexpr int NBN = N / 128;
    __shared__ __align__(16) char SM[2 * 24576];   // [db][As 16K | Bs 8K]
    const int tid = threadIdx.x;
    const int wid = tid >> 6;                      // 0..7
    const int lane = tid & 63;
    const int nwg = gridDim.x;                     // divisible by 8
    const int wg = (blockIdx.x & 7) * (nwg >> 3) + (blockIdx.x >> 3);
    const int bm = wg / NBN, bn = wg % NBN;
    const int wr = (wid >> 1) * 64;                // 0,64,128,192
    const int wc = (wid & 1) * 64;                 // 0,64
    const int l15 = lane & 15;
    const int lhi = lane >> 4;

    f32x4 acc[4][4] = {};

    const int row0 = tid >> 2, colb0 = (tid & 3) * 16;   // row0 in [0,128)
    const char* Abase = (const char*)(A + (size_t)(bm * 256) * K);
    const char* Bbase = (const char*)(Bt + (size_t)(bn * 128) * K);
    constexpr size_t rowstride = (size_t)K * 2;

    auto STAGE = [&](int db, int s) {
        const size_t o0 = (size_t)row0 * rowstride + (size_t)s * 64 + colb0;
        const size_t o1 = o0 + 128 * rowstride;    // rows 128..255
        char* As = SM + db * 24576;
        char* Bs = As + 16384;
        gll16(Abase + o0, As + tid * 16);
        gll16(Abase + o1, As + 8192 + tid * 16);
        gll16(Bbase + o0, Bs + tid * 16);
    };
    auto COMPUTE = [&](int db) {
        const __hip_bfloat16* As = (const __hip_bfloat16*)(SM + db * 24576);
        const __hip_bfloat16* Bs = As + 8192;      // 16384 bytes
        bf16x8 af[4], bf4[4];
#pragma unroll
        for (int m = 0; m < 4; ++m)
            af[m] = *(const bf16x8*)(As + (wr + m * 16 + l15) * 32 + lhi * 8);
#pragma unroll
        for (int n = 0; n < 4; ++n)
            bf4[n] = *(const bf16x8*)(Bs + (wc + n * 16 + l15) * 32 + lhi * 8);
#pragma unroll
        for (int m = 0; m < 4; ++m)
#pragma unroll
            for (int n = 0; n < 4; ++n)
                acc[m][n] = __builtin_amdgcn_mfma_f32_16x16x32_bf16(af[m], bf4[n], acc[m][n], 0, 0, 0);
    };

    STAGE(0, 0);
    for (int s = 0; s < NT - 1; ++s) {
        const int cur = s & 1;
        STAGE(cur ^ 1, s + 1);
        asm volatile("s_waitcnt vmcnt(3)" ::: "memory");
        __builtin_amdgcn_s_barrier();
        __builtin_amdgcn_sched_barrier(0);
        COMPUTE(cur);
        __builtin_amdgcn_sched_barrier(0);
        __builtin_amdgcn_s_barrier();
    }
    asm volatile("s_waitcnt vmcnt(0)" ::: "memory");
    __builtin_amdgcn_s_barrier();
    __builtin_amdgcn_sched_barrier(0);
    COMPUTE((NT - 1) & 1);

    const int rbase = bm * 256 + wr + lhi * 4;
    const int cbase = bn * 128 + wc + l15;
#pragma unroll
    for (int n = 0; n < 4; ++n) {
        const int gc = cbase + n * 16;
        const float bv = bias[gc];
#pragma unroll
        for (int m = 0; m < 4; ++m) {
#pragma unroll
            for (int i = 0; i < 4; ++i) {
                const int gr = rbase + m * 16 + i;
                const size_t o = (size_t)gr * N + gc;
                float v = acc[m][n][i] + bv;
                if (EPI == 1) {
                    ((float*)outp)[o] = v + resid[o];
                } else {
                    v = 0.5f * v * (1.f + erff(v * 0.70710678118f));
                    ((__hip_bfloat16*)outp)[o] = __float2bfloat16(v);
                }
            }
        }
    }
}

// ---------- attention state partials: s8[split][bh][d][e] = sum_n k*v over split ----------
__global__ __launch_bounds__(256) void attn_state_kernel(const _Float16* __restrict__ Kf,
                                                         const _Float16* __restrict__ Vf,
                                                         float* __restrict__ s8) {
    const int bh = blockIdx.x;
    const int b = bh >> 4, h = bh & 15;
    const int n0 = blockIdx.y * 512;
    __shared__ float klds[64][64];
    __shared__ float vlds[64][64];
    const int t = threadIdx.x;
    const int r = t >> 2, cc = (t & 3) * 16;
    const int d = t >> 2, e0 = (t & 3) * 16;
    float s[16] = {};

    for (int c = 0; c < 512; c += 64) {
        const size_t m = (size_t)b * 4096 + n0 + c + r;
        const _Float16* kb = Kf + m * 1024 + h * 64;
        const _Float16* vb = Vf + m * 1024 + h * 64;
        const f16x8 k0 = *(const f16x8*)(kb + cc);
        const f16x8 k1 = *(const f16x8*)(kb + cc + 8);
        const f16x8 v0 = *(const f16x8*)(vb + cc);
        const f16x8 v1 = *(const f16x8*)(vb + cc + 8);
        __syncthreads();
#pragma unroll
        for (int j = 0; j < 8; ++j) {
            klds[r][cc + j]     = (float)k0[j];
            klds[r][cc + 8 + j] = (float)k1[j];
            vlds[r][cc + j]     = (float)v0[j];
            vlds[r][cc + 8 + j] = (float)v1[j];
        }
        __syncthreads();
#pragma unroll 8
        for (int n = 0; n < 64; ++n) {
            const float kk = klds[n][d];
            const float4* vp = (const float4*)&vlds[n][e0];
            const float4 a0 = vp[0], a1 = vp[1], a2 = vp[2], a3 = vp[3];
            s[0]  += kk * a0.x; s[1]  += kk * a0.y; s[2]  += kk * a0.z; s[3]  += kk * a0.w;
            s[4]  += kk * a1.x; s[5]  += kk * a1.y; s[6]  += kk * a1.z; s[7]  += kk * a1.w;
            s[8]  += kk * a2.x; s[9]  += kk * a2.y; s[10] += kk * a2.z; s[11] += kk * a2.w;
            s[12] += kk * a3.x; s[13] += kk * a3.y; s[14] += kk * a3.z; s[15] += kk * a3.w;
        }
    }
    float* sp = s8 + (((size_t)blockIdx.y * 64 + bh) * 64 + d) * 64 + e0;
#pragma unroll
    for (int j = 0; j < 16; ++j) sp[j] = s[j];
}

// ---------- state reduce ----------
__global__ __launch_bounds__(256) void state_reduce_kernel(const float* __restrict__ s8,
                                                           float* __restrict__ state) {
    const int idx = blockIdx.x * 256 + threadIdx.x;
    float a = 0.f;
#pragma unroll
    for (int j = 0; j < 8; ++j) a += s8[(size_t)j * 262144 + idx];
    state[idx] = a;
}

// ---------- attention out ----------
__global__ __launch_bounds__(256) void attn_out_kernel(const _Float16* __restrict__ Qf,
                                                       const float* __restrict__ state,
                                                       const double* __restrict__ den,
                                                       __hip_bfloat16* __restrict__ aout) {
    const int bh = blockIdx.x;
    const int b = bh >> 4, h = bh & 15;
    const int n0 = blockIdx.y * 64;
    __shared__ float slds[64][64];
    __shared__ float qlds[64][65];
    const int t = threadIdx.x;
    {
        const float4* sp = (const float4*)(state + (size_t)bh * 4096);
        float4* dp = (float4*)&slds[0][0];
#pragma unroll
        for (int i = 0; i < 4; ++i) dp[i * 256 + t] = sp[i * 256 + t];
    }
    {
        const int r = t >> 2, cc = (t & 3) * 16;
        const size_t m = (size_t)b * 4096 + n0 + r;
        const _Float16* qb = Qf + m * 1024 + h * 64;
        const f16x8 q0 = *(const f16x8*)(qb + cc);
        const f16x8 q1 = *(const f16x8*)(qb + cc + 8);
#pragma unroll
        for (int j = 0; j < 8; ++j) {
            qlds[r][cc + j]     = (float)q0[j];
            qlds[r][cc + 8 + j] = (float)q1[j];
        }
    }
    __syncthreads();
    const int r = t >> 2, e0 = (t & 3) * 16;
    const size_t mrow = (size_t)b * 4096 + n0 + r;
    float o[16] = {};
#pragma unroll 8
    for (int dd = 0; dd < 64; ++dd) {
        const float qv = qlds[r][dd];
        const float4* sp4 = (const float4*)&slds[dd][e0];
        const float4 a0 = sp4[0], a1 = sp4[1], a2 = sp4[2], a3 = sp4[3];
        o[0]  += qv * a0.x; o[1]  += qv * a0.y; o[2]  += qv * a0.z; o[3]  += qv * a0.w;
        o[4]  += qv * a1.x; o[5]  += qv * a1.y; o[6]  += qv * a1.z; o[7]  += qv * a1.w;
        o[8]  += qv * a2.x; o[9]  += qv * a2.y; o[10] += qv * a2.z; o[11] += qv * a2.w;
        o[12] += qv * a3.x; o[13] += qv * a3.y; o[14] += qv * a3.z; o[15] += qv * a3.w;
    }
    const float inv = (float)(1.0 / (den[mrow * 16 + h] + 1e-6));
    __hip_bfloat16* op = aout + mrow * 1024 + h * 64 + e0;
#pragma unroll
    for (int j = 0; j < 16; ++j) op[j] = __float2bfloat16(o[j] * inv);
}

// ---------- launch ----------
extern "C" void kernel_launch(void* const* d_in, const int* in_sizes, int n_in,
                              void* d_out, int out_size, void* d_ws, size_t ws_size,
                              hipStream_t stream) {
    const float* x     = (const float*)d_in[0];
    const float* ln1_w = (const float*)d_in[1];
    const float* ln1_b = (const float*)d_in[2];
    const float* ln2_w = (const float*)d_in[3];
    const float* ln2_b = (const float*)d_in[4];
    const float* qkv_w = (const float*)d_in[5];
    const float* qkv_b = (const float*)d_in[6];
    const float* out_w = (const float*)d_in[7];
    const float* out_b = (const float*)d_in[8];
    const float* fc1_w = (const float*)d_in[9];
    const float* fc1_b = (const float*)d_in[10];
    const float* fc2_w = (const float*)d_in[11];
    const float* fc2_b = (const float*)d_in[12];
    float* out = (float*)d_out;

    char* ws = (char*)d_ws;
    _Float16* Wqh = (_Float16*)(ws + 0);
    _Float16* Wql = (_Float16*)(ws + 2097152);
    _Float16* Wkh = (_Float16*)(ws + 4194304);
    _Float16* Wkl = (_Float16*)(ws + 6291456);
    _Float16* Wvh = (_Float16*)(ws + 8388608);
    __hip_bfloat16* Wo = (__hip_bfloat16*)(ws + 10485760);
    __hip_bfloat16* W1 = (__hip_bfloat16*)(ws + 12582912);
    __hip_bfloat16* W2 = (__hip_bfloat16*)(ws + 20971520);
    _Float16* XH = (_Float16*)(ws + 29360128);
    _Float16* XL = (_Float16*)(ws + 62914560);
    _Float16* QF = (_Float16*)(ws + 96468992);
    _Float16* KF = (_Float16*)(ws + 130023424);
    _Float16* VF = (_Float16*)(ws + 163577856);
    double* DEN  = (double*)(ws + 197132288);
    float* KPART = (float*)(ws + 199229440);
    double* KSUM = (double*)(ws + 199753728);
    float* STATE = (float*)(ws + 199786496);
    float* STATE8 = (float*)XH;                 // 8 MB overlay on dead XH
    __hip_bfloat16* AO   = (__hip_bfloat16*)XL;
    __hip_bfloat16* Hbuf = (__hip_bfloat16*)XL;
    __hip_bfloat16* XN2  = (__hip_bfloat16*)XH;

    cvt_split_kernel<0, true><<<1024, 256, 0, stream>>>(qkv_w, Wqh, Wql);
    cvt_split_kernel<64, true><<<1024, 256, 0, stream>>>(qkv_w, Wkh, Wkl);
    cvt_split_kernel<128, false><<<1024, 256, 0, stream>>>(qkv_w, Wvh, nullptr);
    cvt_kernel<<<1024, 256, 0, stream>>>(out_w, Wo);
    cvt_kernel<<<4096, 256, 0, stream>>>(fc1_w, W1);
    cvt_kernel<<<4096, 256, 0, stream>>>(fc2_w, W2);

    ln_split_kernel<<<16384, 256, 0, stream>>>(x, ln1_w, ln1_b, XH, XL);

    // k (kpart) -> ksum f64 -> q (den) ; v independent
    gemm_f16<1><<<1024, 256, 0, stream>>>(XH, XL, Wkh, Wkl, qkv_b, KF, nullptr, KPART, nullptr);
    ksum_reduce_kernel<<<16, 256, 0, stream>>>(KPART, KSUM);
    gemm_f16<0><<<1024, 256, 0, stream>>>(XH, XL, Wqh, Wql, qkv_b, QF, KSUM, nullptr, DEN);
    gemm_f16<2><<<1024, 256, 0, stream>>>(XH, nullptr, Wvh, nullptr, qkv_b, VF, nullptr, nullptr, nullptr);

    attn_state_kernel<<<dim3(64, 8), 256, 0, stream>>>(KF, VF, STATE8);
    state_reduce_kernel<<<1024, 256, 0, stream>>>(STATE8, STATE);
    attn_out_kernel<<<dim3(64, 64), 256, 0, stream>>>(QF, STATE, DEN, AO);

    // out proj + residual -> x2 (f32, in d_out)
    gemm_bt<1, 1024, 1024><<<512, 512, 0, stream>>>(AO, Wo, out_b, x, out);
    // LN2
    ln_kernel<<<16384, 256, 0, stream>>>(out, ln2_w, ln2_b, XN2);
    // fc1 + gelu
    gemm_bt<2, 4096, 1024><<<2048, 512, 0, stream>>>(XN2, W1, fc1_b, nullptr, Hbuf);
    // fc2 + bias + residual -> final out
    gemm_bt<1, 1024, 4096><<<512, 512, 0, stream>>>(Hbuf, W2, fc2_b, out, out);
}